// Round 2
// baseline (2273.483 us; speedup 1.0000x reference)
//
#include <hip/hip_runtime.h>
#include <cmath>

#define HH   256
#define WW   256
#define NPIX 65536
#define DIM  192
#define HEADS 6
#define HD   32
#define BATCH 2
#define NWIN 1024   // 32*32 windows per batch image

// ---------------- pooling: leaky(mean over 8x8) ----------------
__global__ void pool_kernel(const float* __restrict__ x, float* __restrict__ pooled) {
    int t = blockIdx.x * blockDim.x + threadIdx.x;   // BATCH*DIM*NWIN = 393216
    if (t >= BATCH * DIM * NWIN) return;
    int wx = t & 31, wy = (t >> 5) & 31, bc = t >> 10;
    const float* xp = x + ((size_t)bc << 16) + (size_t)(wy * 8) * WW + wx * 8;
    float s = 0.f;
    #pragma unroll
    for (int r = 0; r < 8; ++r) {
        #pragma unroll
        for (int cc = 0; cc < 8; ++cc) s += xp[r * WW + cc];
    }
    s *= (1.0f / 64.0f);
    pooled[t] = (s >= 0.f) ? s : 0.01f * s;
}

// ---------------- offsets & scales ----------------
__global__ __launch_bounds__(64) void offsc_kernel(
        const float* __restrict__ pooled,
        const float* __restrict__ off_w, const float* __restrict__ off_b,
        const float* __restrict__ sc_w,  const float* __restrict__ sc_b,
        float* __restrict__ offs, float* __restrict__ scales) {
    int blk = blockIdx.x;            // bb*1024 + wy*32+wx
    int bb = blk >> 10; int wxy = blk & 1023;
    __shared__ float pv[DIM];
    for (int c = threadIdx.x; c < DIM; c += 64)
        pv[c] = pooled[((size_t)(bb * DIM + c) << 10) + wxy];
    __syncthreads();
    int o = threadIdx.x;
    if (o < 24) {
        int is_sc = (o >= 12) ? 1 : 0; int oo = o - is_sc * 12;
        const float* wrow = (is_sc ? sc_w : off_w) + oo * DIM;
        float d = 0.f;
        for (int c = 0; c < DIM; ++c) d += wrow[c] * pv[c];
        d += (is_sc ? sc_b : off_b)[oo];
        // channel o' -> (head = o'>>1, ch = o'&1); layout (B*HEADS, 2, 32, 32)
        int idx = ((bb * HEADS + (oo >> 1)) * 2 + (oo & 1)) * NWIN + wxy;
        if (is_sc) scales[idx] = d;
        else       offs[idx]   = d * (1.0f / 32.0f);   // /= wnw (=wnh=32)
    }
}

// ---------------- conv1x1 GEMM: out[o,pix] = sum_c W[o,c]*inp[b,c,pix] + b[o] ----------------
// epilogue scatters into planar layout: plane = (s*BATCH + bb)*DIM + (o - s*DIM), s = o/DIM.
__global__ __launch_bounds__(256) void conv1x1_kernel(
        const float* __restrict__ inp,   // (BATCH, DIM, NPIX)
        const float* __restrict__ Wt,    // (n_out, DIM)
        const float* __restrict__ bias,  // (n_out)
        float* __restrict__ out_base) {
    int pix0 = blockIdx.x << 6;
    int o0   = blockIdx.y << 6;
    int bb   = blockIdx.z;
    int tid  = threadIdx.x;
    __shared__ float Xs[16][64];
    __shared__ float Ws[16][64];
    const float* inp_b = inp + ((size_t)bb * DIM << 16);
    int pr = tid & 15, oc = tid >> 4;
    float acc[4][4] = {};
    for (int k0 = 0; k0 < DIM; k0 += 16) {
        ((float4*)Xs)[tid] = *(const float4*)(inp_b + (size_t)(k0 + (tid >> 4)) * NPIX
                                              + pix0 + ((tid & 15) << 2));
        #pragma unroll
        for (int t = tid; t < 1024; t += 256) {
            int kk = t & 15, o = t >> 4;
            Ws[kk][o] = Wt[(size_t)(o0 + o) * DIM + k0 + kk];
        }
        __syncthreads();
        #pragma unroll
        for (int kk = 0; kk < 16; ++kk) {
            float4 xv = *(const float4*)&Xs[kk][pr << 2];
            float4 wv = *(const float4*)&Ws[kk][oc << 2];
            float xa[4] = {xv.x, xv.y, xv.z, xv.w};
            float wa[4] = {wv.x, wv.y, wv.z, wv.w};
            #pragma unroll
            for (int i = 0; i < 4; ++i)
                #pragma unroll
                for (int j = 0; j < 4; ++j) acc[i][j] += xa[i] * wa[j];
        }
        __syncthreads();
    }
    #pragma unroll
    for (int j = 0; j < 4; ++j) {
        int o = o0 + (oc << 2) + j;
        int s = o / DIM; int within = o - s * DIM;
        float b = bias[o];
        float* outp = out_base + (((size_t)((s * BATCH + bb) * DIM + within)) << 16)
                      + pix0 + (pr << 2);
        float4 r = make_float4(acc[0][j] + b, acc[1][j] + b, acc[2][j] + b, acc[3][j] + b);
        *(float4*)outp = r;
    }
}

// ---------------- fused grid-sample + window attention ----------------
__global__ __launch_bounds__(64) void attn_kernel(
        const float* __restrict__ qkv,    // (3, BATCH, HEADS, HD, NPIX)
        const float* __restrict__ q_lms,  // (BATCH, HEADS, HD, NPIX)
        const float* __restrict__ offs,   // (12, 2, 1024)
        const float* __restrict__ scales, // (12, 2, 1024)
        const float* __restrict__ rpb,    // (225, HEADS)
        float* __restrict__ attn_out) {   // 2 x (BATCH, DIM, NPIX)
    int blk = blockIdx.x;                 // (bb*HEADS+hh)*1024 + wy*32+wx
    int wxy = blk & 1023; int wx = wxy & 31, wy = wxy >> 5;
    int bh = blk >> 10; int hh = bh % HEADS, bb = bh / HEADS;
    int tid = threadIdx.x;
    int pr = tid >> 3, pc = tid & 7;

    __shared__ float k_s[64][36];   // pad 36: rows 16B-aligned for float4 reads
    __shared__ float v_s[64][36];

    // ---- sampling coordinates ----
    float sx = scales[(bh * 2 + 0) * NWIN + wxy];
    float sy = scales[(bh * 2 + 1) * NWIN + wxy];
    float ox = offs[(bh * 2 + 0) * NWIN + wxy];
    float oy = offs[(bh * 2 + 1) * NWIN + wxy];
    const float i255 = 1.0f / 255.0f;
    float gxn = (2.0f * (wx * 8 + pc)) * i255 - 1.0f + (pc - 3.5f) * (2.0f * i255) * sx + ox;
    float gyn = (2.0f * (wy * 8 + pr)) * i255 - 1.0f + (pr - 3.5f) * (2.0f * i255) * sy + oy;
    float gx = (gxn + 1.0f) * 0.5f * 255.0f;
    float gy = (gyn + 1.0f) * 0.5f * 255.0f;
    float x0f = floorf(gx), y0f = floorf(gy);
    float fx1 = gx - x0f, fx0 = 1.f - fx1, fy1 = gy - y0f, fy0 = 1.f - fy1;
    int ix0 = (int)x0f, iy0 = (int)y0f;
    int ix1 = ix0 + 1, iy1 = iy0 + 1;
    bool vx0 = (ix0 >= 0) && (ix0 < WW), vx1 = (ix1 >= 0) && (ix1 < WW);
    bool vy0 = (iy0 >= 0) && (iy0 < HH), vy1 = (iy1 >= 0) && (iy1 < HH);
    float w00 = fx0 * fy0 * (float)(vx0 && vy0), w01 = fx1 * fy0 * (float)(vx1 && vy0);
    float w10 = fx0 * fy1 * (float)(vx0 && vy1), w11 = fx1 * fy1 * (float)(vx1 && vy1);
    int cx0 = min(max(ix0, 0), WW - 1), cx1 = min(max(ix1, 0), WW - 1);
    int cy0 = min(max(iy0, 0), HH - 1), cy1 = min(max(iy1, 0), HH - 1);
    int p00 = cy0 * WW + cx0, p01 = cy0 * WW + cx1;
    int p10 = cy1 * WW + cx0, p11 = cy1 * WW + cx1;

    const float* kb = qkv + (((size_t)((1 * BATCH + bb) * HEADS + hh)) * HD << 16);
    const float* vb = qkv + (((size_t)((2 * BATCH + bb) * HEADS + hh)) * HD << 16);
    #pragma unroll
    for (int c = 0; c < HD; ++c) {
        const float* kp = kb + ((size_t)c << 16);
        k_s[tid][c] = w00 * kp[p00] + w01 * kp[p01] + w10 * kp[p10] + w11 * kp[p11];
        const float* vp = vb + ((size_t)c << 16);
        v_s[tid][c] = w00 * vp[p00] + w01 * vp[p01] + w10 * vp[p10] + w11 * vp[p11];
    }
    __syncthreads();

    int qpix = (wy * 8 + pr) * WW + wx * 8 + pc;
    const float scale = 0.17677669529663687f;  // 32^-0.5
    #pragma unroll 1
    for (int att = 0; att < 2; ++att) {
        const float* qb = (att == 0 ? q_lms : qkv) + (((size_t)(bb * HEADS + hh)) * HD << 16);
        float4 q4[8];
        #pragma unroll
        for (int c4 = 0; c4 < 8; ++c4) {
            q4[c4] = make_float4(qb[((size_t)(c4 * 4 + 0) << 16) + qpix],
                                 qb[((size_t)(c4 * 4 + 1) << 16) + qpix],
                                 qb[((size_t)(c4 * 4 + 2) << 16) + qpix],
                                 qb[((size_t)(c4 * 4 + 3) << 16) + qpix]);
        }
        float a[64]; float m = -1e30f;
        #pragma unroll
        for (int kj = 0; kj < 64; ++kj) {
            const float4* kr = (const float4*)&k_s[kj][0];
            float d = 0.f;
            #pragma unroll
            for (int c4 = 0; c4 < 8; ++c4) {
                float4 kv = kr[c4];
                d += q4[c4].x * kv.x + q4[c4].y * kv.y + q4[c4].z * kv.z + q4[c4].w * kv.w;
            }
            int drow = pr - (kj >> 3) + 7, dcol = pc - (kj & 7) + 7;
            d = d * scale + rpb[(drow * 15 + dcol) * HEADS + hh];
            a[kj] = d; m = fmaxf(m, d);
        }
        float sum = 0.f;
        #pragma unroll
        for (int kj = 0; kj < 64; ++kj) { float e = __expf(a[kj] - m); a[kj] = e; sum += e; }
        float inv = 1.0f / sum;
        float* ob = attn_out + (size_t)att * ((size_t)BATCH * DIM * NPIX)
                    + (((size_t)(bb * HEADS + hh)) * HD << 16) + qpix;
        #pragma unroll 1
        for (int c4 = 0; c4 < 8; ++c4) {
            float4 acc = make_float4(0.f, 0.f, 0.f, 0.f);
            #pragma unroll
            for (int kj = 0; kj < 64; ++kj) {
                float4 vv = *(const float4*)&v_s[kj][c4 << 2];
                float p = a[kj];
                acc.x += p * vv.x; acc.y += p * vv.y; acc.z += p * vv.z; acc.w += p * vv.w;
            }
            ob[((size_t)(c4 * 4 + 0) << 16)] = acc.x * inv;
            ob[((size_t)(c4 * 4 + 1) << 16)] = acc.y * inv;
            ob[((size_t)(c4 * 4 + 2) << 16)] = acc.z * inv;
            ob[((size_t)(c4 * 4 + 3) << 16)] = acc.w * inv;
        }
    }
}

extern "C" void kernel_launch(void* const* d_in, const int* in_sizes, int n_in,
                              void* d_out, int out_size, void* d_ws, size_t ws_size,
                              hipStream_t stream) {
    const float* x      = (const float*)d_in[0];
    const float* lms    = (const float*)d_in[1];
    const float* qkv_w  = (const float*)d_in[2];
    const float* qkv_b  = (const float*)d_in[3];
    const float* off_w  = (const float*)d_in[4];
    const float* off_b  = (const float*)d_in[5];
    const float* sc_w   = (const float*)d_in[6];
    const float* sc_b   = (const float*)d_in[7];
    const float* proj_w = (const float*)d_in[8];
    const float* proj_b = (const float*)d_in[9];
    const float* rpb    = (const float*)d_in[10];

    float* ws = (float*)d_ws;
    float* qkv_x  = ws;                                        // 3*BATCH*DIM*NPIX
    float* q_lms  = qkv_x + (size_t)3 * BATCH * DIM * NPIX;    // BATCH*DIM*NPIX
    float* attn   = q_lms + (size_t)BATCH * DIM * NPIX;        // 2*BATCH*DIM*NPIX
    float* pooled = attn + (size_t)2 * BATCH * DIM * NPIX;     // BATCH*DIM*NWIN
    float* offs   = pooled + (size_t)BATCH * DIM * NWIN;       // 12*2*NWIN
    float* scales = offs + (size_t)12 * 2 * NWIN;              // 12*2*NWIN

    pool_kernel<<<dim3((BATCH * DIM * NWIN + 255) / 256), 256, 0, stream>>>(x, pooled);
    offsc_kernel<<<dim3(BATCH * NWIN), 64, 0, stream>>>(pooled, off_w, off_b, sc_w, sc_b,
                                                        offs, scales);
    conv1x1_kernel<<<dim3(NPIX / 64, (3 * DIM) / 64, BATCH), 256, 0, stream>>>(
        x, qkv_w, qkv_b, qkv_x);
    conv1x1_kernel<<<dim3(NPIX / 64, DIM / 64, BATCH), 256, 0, stream>>>(
        lms, qkv_w, qkv_b, q_lms);
    attn_kernel<<<dim3(BATCH * HEADS * NWIN), 64, 0, stream>>>(
        qkv_x, q_lms, offs, scales, rpb, attn);
    conv1x1_kernel<<<dim3(NPIX / 64, DIM / 64, BATCH), 256, 0, stream>>>(
        attn, proj_w, proj_b, (float*)d_out);
    conv1x1_kernel<<<dim3(NPIX / 64, DIM / 64, BATCH), 256, 0, stream>>>(
        attn + (size_t)BATCH * DIM * NPIX, proj_w, proj_b,
        (float*)d_out + (size_t)BATCH * DIM * NPIX);
}

// Round 3
// 1730.590 us; speedup vs baseline: 1.3137x; 1.3137x over previous
//
#include <hip/hip_runtime.h>
#include <cmath>

#define HH   256
#define WW   256
#define NPIX 65536
#define DIM  192
#define HEADS 6
#define HD   32
#define BATCH 2
#define NWIN 1024   // 32*32 windows per batch image

__device__ inline unsigned short f2bf(float f) {
    unsigned u = __float_as_uint(f);
    u += 0x7fffu + ((u >> 16) & 1u);
    return (unsigned short)(u >> 16);
}
__device__ inline float bf2f(unsigned v16) {   // low 16 bits hold bf16
    return __uint_as_float((v16 & 0xffffu) << 16);
}

// ---------------- pooling: leaky(mean over 8x8) ----------------
__global__ void pool_kernel(const float* __restrict__ x, float* __restrict__ pooled) {
    int t = blockIdx.x * blockDim.x + threadIdx.x;   // BATCH*DIM*NWIN = 393216
    if (t >= BATCH * DIM * NWIN) return;
    int wx = t & 31, wy = (t >> 5) & 31, bc = t >> 10;
    const float* xp = x + ((size_t)bc << 16) + (size_t)(wy * 8) * WW + wx * 8;
    float s = 0.f;
    #pragma unroll
    for (int r = 0; r < 8; ++r) {
        #pragma unroll
        for (int cc = 0; cc < 8; ++cc) s += xp[r * WW + cc];
    }
    s *= (1.0f / 64.0f);
    pooled[t] = (s >= 0.f) ? s : 0.01f * s;
}

// ---------------- offsets & scales ----------------
__global__ __launch_bounds__(64) void offsc_kernel(
        const float* __restrict__ pooled,
        const float* __restrict__ off_w, const float* __restrict__ off_b,
        const float* __restrict__ sc_w,  const float* __restrict__ sc_b,
        float* __restrict__ offs, float* __restrict__ scales) {
    int blk = blockIdx.x;            // bb*1024 + wy*32+wx
    int bb = blk >> 10; int wxy = blk & 1023;
    __shared__ float pv[DIM];
    for (int c = threadIdx.x; c < DIM; c += 64)
        pv[c] = pooled[((size_t)(bb * DIM + c) << 10) + wxy];
    __syncthreads();
    int o = threadIdx.x;
    if (o < 24) {
        int is_sc = (o >= 12) ? 1 : 0; int oo = o - is_sc * 12;
        const float* wrow = (is_sc ? sc_w : off_w) + oo * DIM;
        float d = 0.f;
        for (int c = 0; c < DIM; ++c) d += wrow[c] * pv[c];
        d += (is_sc ? sc_b : off_b)[oo];
        int idx = ((bb * HEADS + (oo >> 1)) * 2 + (oo & 1)) * NWIN + wxy;
        if (is_sc) scales[idx] = d;
        else       offs[idx]   = d * (1.0f / 32.0f);   // /= wnw (=wnh=32)
    }
}

// ---------------- conv1x1 GEMM ----------------
__global__ __launch_bounds__(256) void conv1x1_kernel(
        const float* __restrict__ inp,   // (BATCH, DIM, NPIX)
        const float* __restrict__ Wt,    // (n_out, DIM)
        const float* __restrict__ bias,  // (n_out)
        float* __restrict__ out_base) {
    int pix0 = blockIdx.x << 6;
    int o0   = blockIdx.y << 6;
    int bb   = blockIdx.z;
    int tid  = threadIdx.x;
    __shared__ float Xs[16][64];
    __shared__ float Ws[16][64];
    const float* inp_b = inp + ((size_t)bb * DIM << 16);
    int pr = tid & 15, oc = tid >> 4;
    float acc[4][4] = {};
    for (int k0 = 0; k0 < DIM; k0 += 16) {
        ((float4*)Xs)[tid] = *(const float4*)(inp_b + (size_t)(k0 + (tid >> 4)) * NPIX
                                              + pix0 + ((tid & 15) << 2));
        #pragma unroll
        for (int t = tid; t < 1024; t += 256) {
            int kk = t & 15, o = t >> 4;
            Ws[kk][o] = Wt[(size_t)(o0 + o) * DIM + k0 + kk];
        }
        __syncthreads();
        #pragma unroll
        for (int kk = 0; kk < 16; ++kk) {
            float4 xv = *(const float4*)&Xs[kk][pr << 2];
            float4 wv = *(const float4*)&Ws[kk][oc << 2];
            float xa[4] = {xv.x, xv.y, xv.z, xv.w};
            float wa[4] = {wv.x, wv.y, wv.z, wv.w};
            #pragma unroll
            for (int i = 0; i < 4; ++i)
                #pragma unroll
                for (int j = 0; j < 4; ++j) acc[i][j] += xa[i] * wa[j];
        }
        __syncthreads();
    }
    #pragma unroll
    for (int j = 0; j < 4; ++j) {
        int o = o0 + (oc << 2) + j;
        int s = o / DIM; int within = o - s * DIM;
        float b = bias[o];
        float* outp = out_base + (((size_t)((s * BATCH + bb) * DIM + within)) << 16)
                      + pix0 + (pr << 2);
        float4 r = make_float4(acc[0][j] + b, acc[1][j] + b, acc[2][j] + b, acc[3][j] + b);
        *(float4*)outp = r;
    }
}

// ---------------- gather: bilinear-sample K,V into dense bf16 [win][key][ch] ----------------
__global__ __launch_bounds__(256) void gather_kernel(
        const float* __restrict__ qkv,    // (3, BATCH, HEADS, HD, NPIX)
        const float* __restrict__ offs,   // (12, 2, 1024)
        const float* __restrict__ scales, // (12, 2, 1024)
        unsigned short* __restrict__ ksel,  // (12288, 64, 32) bf16
        unsigned short* __restrict__ vsel) {
    int blk = blockIdx.x;                 // (bb*HEADS+hh)*1024 + wxy
    int wxy = blk & 1023; int wx = wxy & 31, wy = wxy >> 5;
    int bh = blk >> 10; int hh = bh % HEADS, bb = bh / HEADS;
    int lane = threadIdx.x & 63;          // key index
    int chg  = threadIdx.x >> 6;          // channel group (8 ch each)
    int kr = lane >> 3, kc = lane & 7;

    float sx = scales[(bh * 2 + 0) * NWIN + wxy];
    float sy = scales[(bh * 2 + 1) * NWIN + wxy];
    float ox = offs[(bh * 2 + 0) * NWIN + wxy];
    float oy = offs[(bh * 2 + 1) * NWIN + wxy];
    const float i255 = 1.0f / 255.0f;
    float gxn = (2.0f * (wx * 8 + kc)) * i255 - 1.0f + (kc - 3.5f) * (2.0f * i255) * sx + ox;
    float gyn = (2.0f * (wy * 8 + kr)) * i255 - 1.0f + (kr - 3.5f) * (2.0f * i255) * sy + oy;
    float gx = (gxn + 1.0f) * 0.5f * 255.0f;
    float gy = (gyn + 1.0f) * 0.5f * 255.0f;
    float x0f = floorf(gx), y0f = floorf(gy);
    float fx1 = gx - x0f, fx0 = 1.f - fx1, fy1 = gy - y0f, fy0 = 1.f - fy1;
    int ix0 = (int)x0f, iy0 = (int)y0f;
    int ix1 = ix0 + 1, iy1 = iy0 + 1;
    bool vx0 = (ix0 >= 0) && (ix0 < WW), vx1 = (ix1 >= 0) && (ix1 < WW);
    bool vy0 = (iy0 >= 0) && (iy0 < HH), vy1 = (iy1 >= 0) && (iy1 < HH);
    float w00 = fx0 * fy0 * (float)(vx0 && vy0), w01 = fx1 * fy0 * (float)(vx1 && vy0);
    float w10 = fx0 * fy1 * (float)(vx0 && vy1), w11 = fx1 * fy1 * (float)(vx1 && vy1);
    int cx0 = min(max(ix0, 0), WW - 1), cx1 = min(max(ix1, 0), WW - 1);
    int cy0 = min(max(iy0, 0), HH - 1), cy1 = min(max(iy1, 0), HH - 1);
    int p00 = cy0 * WW + cx0, p01 = cy0 * WW + cx1;
    int p10 = cy1 * WW + cx0, p11 = cy1 * WW + cx1;

    const float* kb = qkv + (((size_t)((1 * BATCH + bb) * HEADS + hh)) * HD << 16)
                      + ((size_t)(chg * 8) << 16);
    const float* vb = qkv + (((size_t)((2 * BATCH + bb) * HEADS + hh)) * HD << 16)
                      + ((size_t)(chg * 8) << 16);
    float kv[8], vv[8];
    #pragma unroll
    for (int c = 0; c < 8; ++c) {
        const float* kp = kb + ((size_t)c << 16);
        kv[c] = w00 * kp[p00] + w01 * kp[p01] + w10 * kp[p10] + w11 * kp[p11];
        const float* vp = vb + ((size_t)c << 16);
        vv[c] = w00 * vp[p00] + w01 * vp[p01] + w10 * vp[p10] + w11 * vp[p11];
    }
    size_t obase = (((size_t)blk * 64 + lane) * 32) + chg * 8;
    uint4 sk, sv;
    sk.x = f2bf(kv[0]) | ((unsigned)f2bf(kv[1]) << 16);
    sk.y = f2bf(kv[2]) | ((unsigned)f2bf(kv[3]) << 16);
    sk.z = f2bf(kv[4]) | ((unsigned)f2bf(kv[5]) << 16);
    sk.w = f2bf(kv[6]) | ((unsigned)f2bf(kv[7]) << 16);
    sv.x = f2bf(vv[0]) | ((unsigned)f2bf(vv[1]) << 16);
    sv.y = f2bf(vv[2]) | ((unsigned)f2bf(vv[3]) << 16);
    sv.z = f2bf(vv[4]) | ((unsigned)f2bf(vv[5]) << 16);
    sv.w = f2bf(vv[6]) | ((unsigned)f2bf(vv[7]) << 16);
    *(uint4*)(ksel + obase) = sk;
    *(uint4*)(vsel + obase) = sv;
}

// ---------------- attention (one phase) on dense K/V ----------------
__global__ __launch_bounds__(64) void attn_phase_kernel(
        const float* __restrict__ qsrc,   // (BATCH, HEADS, HD, NPIX)
        const unsigned short* __restrict__ ksel,  // (12288, 64, 32) bf16
        const unsigned short* __restrict__ vsel,
        const float* __restrict__ rpb,    // (225, HEADS)
        float* __restrict__ out) {        // (BATCH, DIM, NPIX)
    int blk = blockIdx.x;                 // (bb*HEADS+hh)*1024 + wxy
    int wxy = blk & 1023; int wx = wxy & 31, wy = wxy >> 5;
    int bh = blk >> 10; int hh = bh % HEADS, bb = bh / HEADS;
    int tid = threadIdx.x;
    int pr = tid >> 3, pc = tid & 7;

    __shared__ float k_s[64][36];
    __shared__ float v_s[64][36];
    __shared__ float rpb_s[225];

    for (int i = tid; i < 225; i += 64) rpb_s[i] = rpb[i * HEADS + hh];

    // prefetch q (independent of staging)
    int qpix = (wy * 8 + pr) * WW + wx * 8 + pc;
    const float* qb = qsrc + (((size_t)(bb * HEADS + hh)) * HD << 16);
    float4 q4[8];
    #pragma unroll
    for (int c4 = 0; c4 < 8; ++c4) {
        q4[c4] = make_float4(qb[((size_t)(c4 * 4 + 0) << 16) + qpix],
                             qb[((size_t)(c4 * 4 + 1) << 16) + qpix],
                             qb[((size_t)(c4 * 4 + 2) << 16) + qpix],
                             qb[((size_t)(c4 * 4 + 3) << 16) + qpix]);
    }

    // stage K,V: 2048 bf16 each = 256 8-elt chunks, 4 iters x 64 lanes
    const uint4* kdp = (const uint4*)(ksel + ((size_t)blk << 11));
    const uint4* vdp = (const uint4*)(vsel + ((size_t)blk << 11));
    #pragma unroll
    for (int i = 0; i < 4; ++i) {
        int e = i * 64 + tid;
        int key = e >> 2, c8 = (e & 3) << 3;
        uint4 pk = kdp[e];
        float* dk = &k_s[key][c8];
        dk[0] = bf2f(pk.x); dk[1] = bf2f(pk.x >> 16);
        dk[2] = bf2f(pk.y); dk[3] = bf2f(pk.y >> 16);
        dk[4] = bf2f(pk.z); dk[5] = bf2f(pk.z >> 16);
        dk[6] = bf2f(pk.w); dk[7] = bf2f(pk.w >> 16);
        uint4 pv = vdp[e];
        float* dv = &v_s[key][c8];
        dv[0] = bf2f(pv.x); dv[1] = bf2f(pv.x >> 16);
        dv[2] = bf2f(pv.y); dv[3] = bf2f(pv.y >> 16);
        dv[4] = bf2f(pv.z); dv[5] = bf2f(pv.z >> 16);
        dv[6] = bf2f(pv.w); dv[7] = bf2f(pv.w >> 16);
    }
    __syncthreads();

    const float scale = 0.17677669529663687f;  // 32^-0.5
    float a[64]; float m = -1e30f;
    #pragma unroll
    for (int kj = 0; kj < 64; ++kj) {
        const float4* kr4 = (const float4*)&k_s[kj][0];
        float d = 0.f;
        #pragma unroll
        for (int c4 = 0; c4 < 8; ++c4) {
            float4 kvv = kr4[c4];
            d += q4[c4].x * kvv.x + q4[c4].y * kvv.y + q4[c4].z * kvv.z + q4[c4].w * kvv.w;
        }
        int drow = pr - (kj >> 3) + 7, dcol = pc - (kj & 7) + 7;
        d = d * scale + rpb_s[drow * 15 + dcol];
        a[kj] = d; m = fmaxf(m, d);
    }
    float sum = 0.f;
    #pragma unroll
    for (int kj = 0; kj < 64; ++kj) { float e = __expf(a[kj] - m); a[kj] = e; sum += e; }
    float inv = 1.0f / sum;
    float* ob = out + (((size_t)(bb * HEADS + hh)) * HD << 16) + qpix;
    #pragma unroll 1
    for (int c4 = 0; c4 < 8; ++c4) {
        float4 acc = make_float4(0.f, 0.f, 0.f, 0.f);
        #pragma unroll
        for (int kj = 0; kj < 64; ++kj) {
            float4 vv = *(const float4*)&v_s[kj][c4 << 2];
            float p = a[kj];
            acc.x += p * vv.x; acc.y += p * vv.y; acc.z += p * vv.z; acc.w += p * vv.w;
        }
        ob[((size_t)(c4 * 4 + 0) << 16)] = acc.x * inv;
        ob[((size_t)(c4 * 4 + 1) << 16)] = acc.y * inv;
        ob[((size_t)(c4 * 4 + 2) << 16)] = acc.z * inv;
        ob[((size_t)(c4 * 4 + 3) << 16)] = acc.w * inv;
    }
}

extern "C" void kernel_launch(void* const* d_in, const int* in_sizes, int n_in,
                              void* d_out, int out_size, void* d_ws, size_t ws_size,
                              hipStream_t stream) {
    const float* x      = (const float*)d_in[0];
    const float* lms    = (const float*)d_in[1];
    const float* qkv_w  = (const float*)d_in[2];
    const float* qkv_b  = (const float*)d_in[3];
    const float* off_w  = (const float*)d_in[4];
    const float* off_b  = (const float*)d_in[5];
    const float* sc_w   = (const float*)d_in[6];
    const float* sc_b   = (const float*)d_in[7];
    const float* proj_w = (const float*)d_in[8];
    const float* proj_b = (const float*)d_in[9];
    const float* rpb    = (const float*)d_in[10];

    const size_t PLANE = (size_t)BATCH * DIM * NPIX;   // 25,165,824 floats
    float* ws = (float*)d_ws;
    float* qkv_x  = ws;                       // 3*PLANE
    float* q_lms  = qkv_x + 3 * PLANE;        // PLANE
    float* pooled = q_lms + PLANE;            // BATCH*DIM*NWIN
    float* offs   = pooled + (size_t)BATCH * DIM * NWIN;
    float* scales = offs + 12 * 2 * NWIN;
    unsigned short* ksel = (unsigned short*)(scales + 12 * 2 * NWIN);  // 25,165,824 bf16
    unsigned short* vsel = ksel + PLANE;      // PLANE bf16 elements each
    float* bufA = qkv_x + PLANE;              // alias K planes (dead after gather)

    pool_kernel<<<dim3((BATCH * DIM * NWIN + 255) / 256), 256, 0, stream>>>(x, pooled);
    offsc_kernel<<<dim3(BATCH * NWIN), 64, 0, stream>>>(pooled, off_w, off_b, sc_w, sc_b,
                                                        offs, scales);
    conv1x1_kernel<<<dim3(NPIX / 64, (3 * DIM) / 64, BATCH), 256, 0, stream>>>(
        x, qkv_w, qkv_b, qkv_x);
    conv1x1_kernel<<<dim3(NPIX / 64, DIM / 64, BATCH), 256, 0, stream>>>(
        lms, qkv_w, qkv_b, q_lms);
    gather_kernel<<<dim3(BATCH * HEADS * NWIN), 256, 0, stream>>>(
        qkv_x, offs, scales, ksel, vsel);
    // phase 0: q from lms
    attn_phase_kernel<<<dim3(BATCH * HEADS * NWIN), 64, 0, stream>>>(
        q_lms, ksel, vsel, rpb, bufA);
    conv1x1_kernel<<<dim3(NPIX / 64, DIM / 64, BATCH), 256, 0, stream>>>(
        bufA, proj_w, proj_b, (float*)d_out);
    // phase 1: q_pan from x's qkv
    attn_phase_kernel<<<dim3(BATCH * HEADS * NWIN), 64, 0, stream>>>(
        qkv_x, ksel, vsel, rpb, bufA);
    conv1x1_kernel<<<dim3(NPIX / 64, DIM / 64, BATCH), 256, 0, stream>>>(
        bufA, proj_w, proj_b, (float*)d_out + PLANE);
}

// Round 4
// 1266.368 us; speedup vs baseline: 1.7953x; 1.3666x over previous
//
#include <hip/hip_runtime.h>
#include <cmath>

#define HH   256
#define WW   256
#define NPIX 65536
#define DIM  192
#define HEADS 6
#define HD   32
#define BATCH 2
#define NWIN 1024   // 32*32 windows per batch image

typedef __attribute__((ext_vector_type(8))) short short8;
typedef __attribute__((ext_vector_type(4))) float f32x4;

__device__ inline unsigned short f2bf(float f) {
    unsigned u = __float_as_uint(f);
    u += 0x7fffu + ((u >> 16) & 1u);
    return (unsigned short)(u >> 16);
}
__device__ inline float bf2f(unsigned v16) {   // low 16 bits hold bf16
    return __uint_as_float((v16 & 0xffffu) << 16);
}

// ---------------- pooling: leaky(mean over 8x8) ----------------
__global__ void pool_kernel(const float* __restrict__ x, float* __restrict__ pooled) {
    int t = blockIdx.x * blockDim.x + threadIdx.x;   // BATCH*DIM*NWIN = 393216
    if (t >= BATCH * DIM * NWIN) return;
    int wx = t & 31, wy = (t >> 5) & 31, bc = t >> 10;
    const float* xp = x + ((size_t)bc << 16) + (size_t)(wy * 8) * WW + wx * 8;
    float s = 0.f;
    #pragma unroll
    for (int r = 0; r < 8; ++r) {
        #pragma unroll
        for (int cc = 0; cc < 8; ++cc) s += xp[r * WW + cc];
    }
    s *= (1.0f / 64.0f);
    pooled[t] = (s >= 0.f) ? s : 0.01f * s;
}

// ---------------- offsets & scales ----------------
__global__ __launch_bounds__(64) void offsc_kernel(
        const float* __restrict__ pooled,
        const float* __restrict__ off_w, const float* __restrict__ off_b,
        const float* __restrict__ sc_w,  const float* __restrict__ sc_b,
        float* __restrict__ offs, float* __restrict__ scales) {
    int blk = blockIdx.x;            // bb*1024 + wy*32+wx
    int bb = blk >> 10; int wxy = blk & 1023;
    __shared__ float pv[DIM];
    for (int c = threadIdx.x; c < DIM; c += 64)
        pv[c] = pooled[((size_t)(bb * DIM + c) << 10) + wxy];
    __syncthreads();
    int o = threadIdx.x;
    if (o < 24) {
        int is_sc = (o >= 12) ? 1 : 0; int oo = o - is_sc * 12;
        const float* wrow = (is_sc ? sc_w : off_w) + oo * DIM;
        float d = 0.f;
        for (int c = 0; c < DIM; ++c) d += wrow[c] * pv[c];
        d += (is_sc ? sc_b : off_b)[oo];
        int idx = ((bb * HEADS + (oo >> 1)) * 2 + (oo & 1)) * NWIN + wxy;
        if (is_sc) scales[idx] = d;
        else       offs[idx]   = d * (1.0f / 32.0f);   // /= wnw (=wnh=32)
    }
}

// ---------------- conv1x1 via split-bf16 MFMA ----------------
// C[o,pix] = sum_c W[o,c]*X[c,pix]; X split hi/lo bf16, W split hi/lo bf16;
// acc = Ah*Bh + Ah*Bl + Al*Bh  (f32 accum; ~1.6e-5 relative input error)
// Block: 256 thr = 4 waves; tile M=64 (wave w: rows w*16..), N=128 pix, K-step 32.
__global__ __launch_bounds__(256) void conv1x1_mfma(
        const float* __restrict__ inp,   // (BATCH, DIM, NPIX)
        const float* __restrict__ Wt,    // (n_out, DIM) row-major
        const float* __restrict__ bias,  // (n_out)
        float* __restrict__ out_base,    // planar scatter: plane=(s*BATCH+bb)*DIM+o%DIM
        int n_otiles) {                  // n_out/64
    // XCD-chunked swizzle: contiguous logical ids (o-tile innermost) per XCD
    int nwg = gridDim.x; int per = nwg >> 3;
    int wg = (blockIdx.x & 7) * per + (blockIdx.x >> 3);
    int otile = wg % n_otiles; int pt = wg / n_otiles;
    int pixtile = pt & 511; int bb = pt >> 9;
    int o0 = otile << 6; int pix0 = pixtile << 7;

    int tid = threadIdx.x;
    int wv = tid >> 6, l = tid & 63;
    int gr = l >> 4, l16 = l & 15;

    __shared__ unsigned lds_u[32 * 132];   // packed (hi | lo<<16), pad 132, XOR swizzle

    const float* inp_b = inp + ((size_t)bb * DIM << 16);
    f32x4 acc[8];
    #pragma unroll
    for (int g = 0; g < 8; ++g) acc[g] = (f32x4){0.f, 0.f, 0.f, 0.f};

    int arow = o0 + wv * 16 + l16;
    int kbase = gr * 8;

    for (int c = 0; c < 6; ++c) {
        int k0 = c * 32;
        // ---- A fragments (W chunk) from global: 8 consecutive k per lane ----
        const float* wp = Wt + (size_t)arow * DIM + k0 + kbase;
        float4 w0 = *(const float4*)wp;
        float4 w1 = *(const float4*)(wp + 4);
        short8 a_hi, a_lo;
        {
            float wf[8] = {w0.x, w0.y, w0.z, w0.w, w1.x, w1.y, w1.z, w1.w};
            #pragma unroll
            for (int i = 0; i < 8; ++i) {
                unsigned short h = f2bf(wf[i]);
                float r = wf[i] - bf2f(h);
                a_hi[i] = (short)h;
                a_lo[i] = (short)f2bf(r);
            }
        }
        // ---- stage X tile [32k][128pix] as packed hi/lo u32 ----
        __syncthreads();
        #pragma unroll
        for (int p = 0; p < 4; ++p) {
            int kk = p * 8 + (tid >> 5);
            int pixl = (tid & 31) << 2;
            float4 xv = *(const float4*)(inp_b + (size_t)(k0 + kk) * NPIX + pix0 + pixl);
            float xf[4] = {xv.x, xv.y, xv.z, xv.w};
            uint4 pk;
            unsigned* pu = (unsigned*)&pk;
            #pragma unroll
            for (int j = 0; j < 4; ++j) {
                unsigned short h = f2bf(xf[j]);
                float r = xf[j] - bf2f(h);
                pu[j] = (unsigned)h | ((unsigned)f2bf(r) << 16);
            }
            *(uint4*)&lds_u[kk * 132 + (pixl ^ ((kk >> 3) << 3))] = pk;
        }
        __syncthreads();
        // ---- MFMA over 8 pixel groups ----
        #pragma unroll
        for (int g = 0; g < 8; ++g) {
            int pp = g * 16 + l16;
            unsigned bv[8];
            #pragma unroll
            for (int i = 0; i < 8; ++i)
                bv[i] = lds_u[(gr * 8 + i) * 132 + (pp ^ (gr << 3))];
            short8 b_hi, b_lo;
            #pragma unroll
            for (int i = 0; i < 8; ++i) {
                b_hi[i] = (short)(bv[i] & 0xffffu);
                b_lo[i] = (short)(bv[i] >> 16);
            }
            acc[g] = __builtin_amdgcn_mfma_f32_16x16x32_bf16(a_hi, b_hi, acc[g], 0, 0, 0);
            acc[g] = __builtin_amdgcn_mfma_f32_16x16x32_bf16(a_hi, b_lo, acc[g], 0, 0, 0);
            acc[g] = __builtin_amdgcn_mfma_f32_16x16x32_bf16(a_lo, b_hi, acc[g], 0, 0, 0);
        }
    }
    // ---- epilogue: D row=(l>>4)*4+r (o), col=l&15 (pix) ----
    #pragma unroll
    for (int r = 0; r < 4; ++r) {
        int orow = o0 + wv * 16 + gr * 4 + r;
        int s = orow / DIM; int wo = orow - s * DIM;
        float b = bias[orow];
        float* op = out_base + (((size_t)((s * BATCH + bb) * DIM + wo)) << 16) + pix0 + l16;
        #pragma unroll
        for (int g = 0; g < 8; ++g) op[g * 16] = acc[g][r] + b;
    }
}

// ---------------- gather: bilinear-sample K,V into dense bf16 [win][key][ch] ----------------
__global__ __launch_bounds__(256) void gather_kernel(
        const float* __restrict__ qkv,    // (3, BATCH, HEADS, HD, NPIX)
        const float* __restrict__ offs,   // (12, 2, 1024)
        const float* __restrict__ scales, // (12, 2, 1024)
        unsigned short* __restrict__ ksel,  // (12288, 64, 32) bf16
        unsigned short* __restrict__ vsel) {
    int blk = blockIdx.x;                 // (bb*HEADS+hh)*1024 + wxy
    int wxy = blk & 1023; int wx = wxy & 31, wy = wxy >> 5;
    int bh = blk >> 10; int hh = bh % HEADS, bb = bh / HEADS;
    int lane = threadIdx.x & 63;          // key index
    int chg  = threadIdx.x >> 6;          // channel group (8 ch each)
    int kr = lane >> 3, kc = lane & 7;

    float sx = scales[(bh * 2 + 0) * NWIN + wxy];
    float sy = scales[(bh * 2 + 1) * NWIN + wxy];
    float ox = offs[(bh * 2 + 0) * NWIN + wxy];
    float oy = offs[(bh * 2 + 1) * NWIN + wxy];
    const float i255 = 1.0f / 255.0f;
    float gxn = (2.0f * (wx * 8 + kc)) * i255 - 1.0f + (kc - 3.5f) * (2.0f * i255) * sx + ox;
    float gyn = (2.0f * (wy * 8 + kr)) * i255 - 1.0f + (kr - 3.5f) * (2.0f * i255) * sy + oy;
    float gx = (gxn + 1.0f) * 0.5f * 255.0f;
    float gy = (gyn + 1.0f) * 0.5f * 255.0f;
    float x0f = floorf(gx), y0f = floorf(gy);
    float fx1 = gx - x0f, fx0 = 1.f - fx1, fy1 = gy - y0f, fy0 = 1.f - fy1;
    int ix0 = (int)x0f, iy0 = (int)y0f;
    int ix1 = ix0 + 1, iy1 = iy0 + 1;
    bool vx0 = (ix0 >= 0) && (ix0 < WW), vx1 = (ix1 >= 0) && (ix1 < WW);
    bool vy0 = (iy0 >= 0) && (iy0 < HH), vy1 = (iy1 >= 0) && (iy1 < HH);
    float w00 = fx0 * fy0 * (float)(vx0 && vy0), w01 = fx1 * fy0 * (float)(vx1 && vy0);
    float w10 = fx0 * fy1 * (float)(vx0 && vy1), w11 = fx1 * fy1 * (float)(vx1 && vy1);
    int cx0 = min(max(ix0, 0), WW - 1), cx1 = min(max(ix1, 0), WW - 1);
    int cy0 = min(max(iy0, 0), HH - 1), cy1 = min(max(iy1, 0), HH - 1);
    int p00 = cy0 * WW + cx0, p01 = cy0 * WW + cx1;
    int p10 = cy1 * WW + cx0, p11 = cy1 * WW + cx1;

    const float* kb = qkv + (((size_t)((1 * BATCH + bb) * HEADS + hh)) * HD << 16)
                      + ((size_t)(chg * 8) << 16);
    const float* vb = qkv + (((size_t)((2 * BATCH + bb) * HEADS + hh)) * HD << 16)
                      + ((size_t)(chg * 8) << 16);
    float kv[8], vv[8];
    #pragma unroll
    for (int c = 0; c < 8; ++c) {
        const float* kp = kb + ((size_t)c << 16);
        kv[c] = w00 * kp[p00] + w01 * kp[p01] + w10 * kp[p10] + w11 * kp[p11];
        const float* vp = vb + ((size_t)c << 16);
        vv[c] = w00 * vp[p00] + w01 * vp[p01] + w10 * vp[p10] + w11 * vp[p11];
    }
    size_t obase = (((size_t)blk * 64 + lane) * 32) + chg * 8;
    uint4 sk, sv;
    sk.x = f2bf(kv[0]) | ((unsigned)f2bf(kv[1]) << 16);
    sk.y = f2bf(kv[2]) | ((unsigned)f2bf(kv[3]) << 16);
    sk.z = f2bf(kv[4]) | ((unsigned)f2bf(kv[5]) << 16);
    sk.w = f2bf(kv[6]) | ((unsigned)f2bf(kv[7]) << 16);
    sv.x = f2bf(vv[0]) | ((unsigned)f2bf(vv[1]) << 16);
    sv.y = f2bf(vv[2]) | ((unsigned)f2bf(vv[3]) << 16);
    sv.z = f2bf(vv[4]) | ((unsigned)f2bf(vv[5]) << 16);
    sv.w = f2bf(vv[6]) | ((unsigned)f2bf(vv[7]) << 16);
    *(uint4*)(ksel + obase) = sk;
    *(uint4*)(vsel + obase) = sv;
}

// ---------------- attention (one phase) on dense K/V ----------------
__global__ __launch_bounds__(64) void attn_phase_kernel(
        const float* __restrict__ qsrc,   // (BATCH, HEADS, HD, NPIX)
        const unsigned short* __restrict__ ksel,  // (12288, 64, 32) bf16
        const unsigned short* __restrict__ vsel,
        const float* __restrict__ rpb,    // (225, HEADS)
        float* __restrict__ out) {        // (BATCH, DIM, NPIX)
    int blk = blockIdx.x;                 // (bb*HEADS+hh)*1024 + wxy
    int wxy = blk & 1023; int wx = wxy & 31, wy = wxy >> 5;
    int bh = blk >> 10; int hh = bh % HEADS, bb = bh / HEADS;
    int tid = threadIdx.x;
    int pr = tid >> 3, pc = tid & 7;

    __shared__ float k_s[64][36];
    __shared__ float v_s[64][36];
    __shared__ float rpb_s[225];

    for (int i = tid; i < 225; i += 64) rpb_s[i] = rpb[i * HEADS + hh];

    int qpix = (wy * 8 + pr) * WW + wx * 8 + pc;
    const float* qb = qsrc + (((size_t)(bb * HEADS + hh)) * HD << 16);
    float4 q4[8];
    #pragma unroll
    for (int c4 = 0; c4 < 8; ++c4) {
        q4[c4] = make_float4(qb[((size_t)(c4 * 4 + 0) << 16) + qpix],
                             qb[((size_t)(c4 * 4 + 1) << 16) + qpix],
                             qb[((size_t)(c4 * 4 + 2) << 16) + qpix],
                             qb[((size_t)(c4 * 4 + 3) << 16) + qpix]);
    }

    const uint4* kdp = (const uint4*)(ksel + ((size_t)blk << 11));
    const uint4* vdp = (const uint4*)(vsel + ((size_t)blk << 11));
    #pragma unroll
    for (int i = 0; i < 4; ++i) {
        int e = i * 64 + tid;
        int key = e >> 2, c8 = (e & 3) << 3;
        uint4 pk = kdp[e];
        float* dk = &k_s[key][c8];
        dk[0] = bf2f(pk.x); dk[1] = bf2f(pk.x >> 16);
        dk[2] = bf2f(pk.y); dk[3] = bf2f(pk.y >> 16);
        dk[4] = bf2f(pk.z); dk[5] = bf2f(pk.z >> 16);
        dk[6] = bf2f(pk.w); dk[7] = bf2f(pk.w >> 16);
        uint4 pv = vdp[e];
        float* dv = &v_s[key][c8];
        dv[0] = bf2f(pv.x); dv[1] = bf2f(pv.x >> 16);
        dv[2] = bf2f(pv.y); dv[3] = bf2f(pv.y >> 16);
        dv[4] = bf2f(pv.z); dv[5] = bf2f(pv.z >> 16);
        dv[6] = bf2f(pv.w); dv[7] = bf2f(pv.w >> 16);
    }
    __syncthreads();

    const float scale = 0.17677669529663687f;  // 32^-0.5
    float a[64]; float m = -1e30f;
    #pragma unroll
    for (int kj = 0; kj < 64; ++kj) {
        const float4* kr4 = (const float4*)&k_s[kj][0];
        float d = 0.f;
        #pragma unroll
        for (int c4 = 0; c4 < 8; ++c4) {
            float4 kvv = kr4[c4];
            d += q4[c4].x * kvv.x + q4[c4].y * kvv.y + q4[c4].z * kvv.z + q4[c4].w * kvv.w;
        }
        int drow = pr - (kj >> 3) + 7, dcol = pc - (kj & 7) + 7;
        d = d * scale + rpb_s[drow * 15 + dcol];
        a[kj] = d; m = fmaxf(m, d);
    }
    float sum = 0.f;
    #pragma unroll
    for (int kj = 0; kj < 64; ++kj) { float e = __expf(a[kj] - m); a[kj] = e; sum += e; }
    float inv = 1.0f / sum;
    float* ob = out + (((size_t)(bb * HEADS + hh)) * HD << 16) + qpix;
    #pragma unroll 1
    for (int c4 = 0; c4 < 8; ++c4) {
        float4 acc = make_float4(0.f, 0.f, 0.f, 0.f);
        #pragma unroll
        for (int kj = 0; kj < 64; ++kj) {
            float4 vv = *(const float4*)&v_s[kj][c4 << 2];
            float p = a[kj];
            acc.x += p * vv.x; acc.y += p * vv.y; acc.z += p * vv.z; acc.w += p * vv.w;
        }
        ob[((size_t)(c4 * 4 + 0) << 16)] = acc.x * inv;
        ob[((size_t)(c4 * 4 + 1) << 16)] = acc.y * inv;
        ob[((size_t)(c4 * 4 + 2) << 16)] = acc.z * inv;
        ob[((size_t)(c4 * 4 + 3) << 16)] = acc.w * inv;
    }
}

extern "C" void kernel_launch(void* const* d_in, const int* in_sizes, int n_in,
                              void* d_out, int out_size, void* d_ws, size_t ws_size,
                              hipStream_t stream) {
    const float* x      = (const float*)d_in[0];
    const float* lms    = (const float*)d_in[1];
    const float* qkv_w  = (const float*)d_in[2];
    const float* qkv_b  = (const float*)d_in[3];
    const float* off_w  = (const float*)d_in[4];
    const float* off_b  = (const float*)d_in[5];
    const float* sc_w   = (const float*)d_in[6];
    const float* sc_b   = (const float*)d_in[7];
    const float* proj_w = (const float*)d_in[8];
    const float* proj_b = (const float*)d_in[9];
    const float* rpb    = (const float*)d_in[10];

    const size_t PLANE = (size_t)BATCH * DIM * NPIX;   // 25,165,824 floats
    float* ws = (float*)d_ws;
    float* qkv_x  = ws;                       // 3*PLANE
    float* q_lms  = qkv_x + 3 * PLANE;        // PLANE
    float* pooled = q_lms + PLANE;            // BATCH*DIM*NWIN
    float* offs   = pooled + (size_t)BATCH * DIM * NWIN;
    float* scales = offs + 12 * 2 * NWIN;
    unsigned short* ksel = (unsigned short*)(scales + 12 * 2 * NWIN);
    unsigned short* vsel = ksel + PLANE;      // PLANE bf16 elements each
    float* bufA = qkv_x + PLANE;              // alias K planes (dead after gather)

    pool_kernel<<<dim3((BATCH * DIM * NWIN + 255) / 256), 256, 0, stream>>>(x, pooled);
    offsc_kernel<<<dim3(BATCH * NWIN), 64, 0, stream>>>(pooled, off_w, off_b, sc_w, sc_b,
                                                        offs, scales);
    conv1x1_mfma<<<dim3(9 * 512 * BATCH), 256, 0, stream>>>(x, qkv_w, qkv_b, qkv_x, 9);
    conv1x1_mfma<<<dim3(3 * 512 * BATCH), 256, 0, stream>>>(lms, qkv_w, qkv_b, q_lms, 3);
    gather_kernel<<<dim3(BATCH * HEADS * NWIN), 256, 0, stream>>>(
        qkv_x, offs, scales, ksel, vsel);
    // phase 0: q from lms
    attn_phase_kernel<<<dim3(BATCH * HEADS * NWIN), 64, 0, stream>>>(
        q_lms, ksel, vsel, rpb, bufA);
    conv1x1_mfma<<<dim3(3 * 512 * BATCH), 256, 0, stream>>>(
        bufA, proj_w, proj_b, (float*)d_out, 3);
    // phase 1: q_pan from x's qkv
    attn_phase_kernel<<<dim3(BATCH * HEADS * NWIN), 64, 0, stream>>>(
        qkv_x, ksel, vsel, rpb, bufA);
    conv1x1_mfma<<<dim3(3 * 512 * BATCH), 256, 0, stream>>>(
        bufA, proj_w, proj_b, (float*)d_out + PLANE, 3);
}